// Round 9
// baseline (278.932 us; speedup 1.0000x reference)
//
#include <hip/hip_runtime.h>
#include <hip/hip_fp16.h>
#include <stdint.h>

// Luong attention: out = softmax(Q K^T) K,  B=16, Tq=Tk=D=1024, fp32 in/out.
//
// Swizzled fragment-major layout (per 1024x1024 batch):
//   addr_halfs(r, c) = (c>>5)*32768 + r*32 + (c&31)
// so a 16x16x32 MFMA fragment read (lane = n16*32 + quad*8) is a contiguous
// 1KB wave-coalesced global_load_dwordx4.
//
// R12 lesson: doubling occupancy (2->4 waves/SIMD) left scores at exactly
// 80us -> the kernel is PHASE-SERIALIZED (stage->K-loop->softmax->P-scatter,
// all waves barrier-synced), each phase at its own memory ceiling. More waves
// cannot help; deleting phases can.
// R13: FUSION. ctx is folded into scores: P never goes to global. After
// softmax, each 512-key half of P is written into the same 64KiB LDS buffer
// (qlds is dead; P uses the IDENTICAL swizzled layout, so the PV A-frag read
// reuses aoff verbatim), then a PV loop (clone of the QK loop, B-frags from
// encTsw with ctx's addressing) accumulates out = P @ enc. Pass-1's P is held
// packed fp16 (32 VGPR) so acc_qk dies early; peak ~230 VGPR under the 256
// cap of __launch_bounds__(512,2). Eliminates: p16 HBM round-trip (32MB write
// + 64MB read), the 64-scalar-2B-store P scatter, and the ctx launch.
//
// [cvt]   enc f32 -> encsw (swizzled) + encTsw (LDS 64x64 transpose, swizzled)
// [fused] stage Q->LDS fp16 (2 phases); S = Q K^T; softmax; P->LDS (2 halves);
//         out = P @ enc (A from LDS, B from encTsw); store out fp32.
// Workspace: encsw 32MiB | encTsw 32MiB = 64MiB.

typedef _Float16 half_t;
typedef __attribute__((ext_vector_type(8))) _Float16 f16x8;
typedef __attribute__((ext_vector_type(2))) _Float16 f16x2;
typedef __attribute__((ext_vector_type(4))) float f32x4;

// ---------------------------------------------------------------------------
// Kernel 1: enc fp32 -> fp16 swizzled (direct + transposed).
// grid (rt=16, ct=16, b=16), block 256.
// ---------------------------------------------------------------------------
__global__ __launch_bounds__(256) void cvt_kernel(
    const float* __restrict__ enc,
    half_t* __restrict__ encsw, half_t* __restrict__ encTsw) {
    __shared__ half_t lt[64 * 65];  // pad 65: conflict-free transpose
    const int b = blockIdx.z;
    const int rt = blockIdx.x, ct = blockIdx.y;
    const int t = threadIdx.x;
    const int r = t >> 2;           // local row 0..63
    const int c0 = (t & 3) << 4;    // local col segment {0,16,32,48}
    const size_t bofs = (size_t)b << 20;

    const float* src = enc + bofs + (size_t)(rt * 64 + r) * 1024 + ct * 64 + c0;
    const float4* s4 = (const float4*)src;
    const float4 f0 = s4[0];
    const float4 f1 = s4[1];
    const float4 f2 = s4[2];
    const float4 f3 = s4[3];

    union { half_t h[16]; uint4 q[2]; } v;
    v.h[0]  = (half_t)f0.x; v.h[1]  = (half_t)f0.y;
    v.h[2]  = (half_t)f0.z; v.h[3]  = (half_t)f0.w;
    v.h[4]  = (half_t)f1.x; v.h[5]  = (half_t)f1.y;
    v.h[6]  = (half_t)f1.z; v.h[7]  = (half_t)f1.w;
    v.h[8]  = (half_t)f2.x; v.h[9]  = (half_t)f2.y;
    v.h[10] = (half_t)f2.z; v.h[11] = (half_t)f2.w;
    v.h[12] = (half_t)f3.x; v.h[13] = (half_t)f3.y;
    v.h[14] = (half_t)f3.z; v.h[15] = (half_t)f3.w;

    // direct swizzled write: element (gr, gc+i) -> (gc>>5)*32768 + gr*32 + (gc&31) + i
    {
        const int gr = rt * 64 + r, gc = ct * 64 + c0;
        half_t* dst = encsw + bofs
                      + (size_t)(gc >> 5) * 32768 + gr * 32 + (gc & 31);
        ((uint4*)dst)[0] = v.q[0];
        ((uint4*)dst)[1] = v.q[1];
    }

#pragma unroll
    for (int i = 0; i < 16; ++i) lt[r * 65 + c0 + i] = v.h[i];
    __syncthreads();
    // thread now holds (key = rt*64 + c0 + i, d = ct*64 + r), keys contiguous
    union { half_t h[16]; uint4 q[2]; } w;
#pragma unroll
    for (int i = 0; i < 16; ++i) w.h[i] = lt[(c0 + i) * 65 + r];
    const int gk = rt * 64 + c0, gd = ct * 64 + r;
    half_t* dstT = encTsw + bofs
                   + (size_t)(gk >> 5) * 32768 + gd * 32 + (gk & 31);
    ((uint4*)dstT)[0] = w.q[0];
    ((uint4*)dstT)[1] = w.q[1];
}

// ---------------------------------------------------------------------------
// Kernel 2 (FUSED): scores + softmax + context. grid 256 x 512 thr (8 waves).
// Block = (batch, 64 q-rows). QK: wave w owns keys {h*512 + w*64}, h=0,1,
// acc_qk[4][8]. PV: wave w owns out-cols d = w*128..+128, acc_pv[4][8].
// Q and P time-share one 64KiB LDS buffer (identical swizzled layout; the
// frag read offsets aoff[] serve both).
// ---------------------------------------------------------------------------
__global__ __launch_bounds__(512, 2) void fused_kernel(
    const float* __restrict__ dec, const half_t* __restrict__ encsw,
    const half_t* __restrict__ encTsw, float* __restrict__ out) {
    // 64 KiB: qlds for QK, then red/redg (softmax), then plds for PV.
    __shared__ __align__(16) unsigned char smem[65536];
    half_t* qlds = (half_t*)smem;           // [16 chunks][64 rows][32 cols]
    half_t* plds = (half_t*)smem;           // same region, same layout (P)
    float* red = (float*)smem;              // [512]
    float* redg = (float*)(smem + 2048);    // [64]

    const int l = blockIdx.x;
    const int xcd = l & 7, idx = l >> 3;
    const int b = xcd + ((idx >> 4) << 3);   // 2 batches per XCD: enc* L2-resident
    const int qbase = (idx & 15) * 64;

    const int tid = threadIdx.x;
    const int w = tid >> 6, lane = tid & 63, quad = lane >> 4, n16 = lane & 15;
    const int laneoff = n16 * 32 + quad * 8;   // frag lane offset within 1KB chunk
    const size_t bofs = (size_t)b << 20;

    // staging decomposition (both phases): 8 threads per row
    const int sr = tid >> 3;       // 0..63 local row
    const int sp = tid & 7;        // 0..7
    const int sg = (sr >> 1) & 3;  // slot-XOR key
    const float* srcrow = dec + bofs + (size_t)(qbase + sr) * 1024;

    // frag-read LDS offsets (halfs): row lr = rb*16+n16, slot quad^g
    int aoff[4];
#pragma unroll
    for (int rb = 0; rb < 4; ++rb) {
        const int lr = rb * 16 + n16;
        aoff[rb] = lr * 32 + ((quad ^ ((lr >> 1) & 3)) << 3);
    }

    f32x4 acc[4][8];
#pragma unroll
    for (int rb = 0; rb < 4; ++rb)
#pragma unroll
        for (int cf = 0; cf < 8; ++cf) acc[rb][cf] = (f32x4){0.f, 0.f, 0.f, 0.f};

    // ================= QK^T: S = Q K^T (2 staged phases) =================
#pragma unroll
    for (int ph = 0; ph < 2; ++ph) {
        if (ph) __syncthreads();   // all phase-0 qlds reads done before rewrite
#pragma unroll
        for (int k = 0; k < 4; ++k) {
            const int c0 = sp * 16 + k * 128;          // local col 0..511
            const float4* spv = (const float4*)(srcrow + ph * 512 + c0);
            const float4 a0 = spv[0], a1 = spv[1], a2 = spv[2], a3 = spv[3];
            union { half_t h[16]; uint4 q[2]; } u;
            u.h[0]  = (half_t)a0.x; u.h[1]  = (half_t)a0.y;
            u.h[2]  = (half_t)a0.z; u.h[3]  = (half_t)a0.w;
            u.h[4]  = (half_t)a1.x; u.h[5]  = (half_t)a1.y;
            u.h[6]  = (half_t)a1.z; u.h[7]  = (half_t)a1.w;
            u.h[8]  = (half_t)a2.x; u.h[9]  = (half_t)a2.y;
            u.h[10] = (half_t)a2.z; u.h[11] = (half_t)a2.w;
            u.h[12] = (half_t)a3.x; u.h[13] = (half_t)a3.y;
            u.h[14] = (half_t)a3.z; u.h[15] = (half_t)a3.w;
            const int chunk = c0 >> 5;                 // local chunk 0..15
            const int s0 = (c0 & 31) >> 3;             // {0,2}
            half_t* base = qlds + chunk * 2048 + sr * 32;
            ((uint4*)(base + ((s0 ^ sg) << 3)))[0] = u.q[0];
            ((uint4*)(base + (((s0 + 1) ^ sg) << 3)))[0] = u.q[1];
        }
        __syncthreads();

        for (int dcl = 0; dcl < 16; ++dcl) {
            const int dc = ph * 16 + dcl;
            const half_t* ec = encsw + bofs + (size_t)dc * 32768;
            f16x8 bf[8];
#pragma unroll
            for (int h = 0; h < 2; ++h)
#pragma unroll
                for (int cb = 0; cb < 4; ++cb)
                    bf[h * 4 + cb] = *(const f16x8*)(
                        ec + (h * 512 + w * 64 + cb * 16) * 32 + laneoff);
            f16x8 af[4];
#pragma unroll
            for (int rb = 0; rb < 4; ++rb)
                af[rb] = *(const f16x8*)(qlds + dcl * 2048 + aoff[rb]);
#pragma unroll
            for (int rb = 0; rb < 4; ++rb)
#pragma unroll
                for (int cf = 0; cf < 8; ++cf)
                    acc[rb][cf] = __builtin_amdgcn_mfma_f32_16x16x32_f16(
                        af[rb], bf[cf], acc[rb][cf], 0, 0, 0);
        }
    }
    __syncthreads();  // qlds dead; red/redg alias it from here on

    // ======================= softmax (rows of S) =========================
    float mrow[4][4], srow[4][4];
#pragma unroll
    for (int rb = 0; rb < 4; ++rb)
#pragma unroll
        for (int r = 0; r < 4; ++r) {
            float m = -1e30f;
#pragma unroll
            for (int cf = 0; cf < 8; ++cf) m = fmaxf(m, acc[rb][cf][r]);
#pragma unroll
            for (int off = 1; off < 16; off <<= 1)
                m = fmaxf(m, __shfl_xor(m, off, 64));
            mrow[rb][r] = m;
        }
    if (n16 == 0) {
#pragma unroll
        for (int rb = 0; rb < 4; ++rb)
#pragma unroll
            for (int r = 0; r < 4; ++r)
                red[w * 64 + rb * 16 + quad * 4 + r] = mrow[rb][r];
    }
    __syncthreads();
    if (tid < 64) {
        float g = red[tid];
#pragma unroll
        for (int ww = 1; ww < 8; ++ww) g = fmaxf(g, red[ww * 64 + tid]);
        redg[tid] = g;
    }
    __syncthreads();
#pragma unroll
    for (int rb = 0; rb < 4; ++rb)
#pragma unroll
        for (int r = 0; r < 4; ++r) mrow[rb][r] = redg[rb * 16 + quad * 4 + r];
    __syncthreads();  // maxes consumed; red reused for sums

#pragma unroll
    for (int rb = 0; rb < 4; ++rb)
#pragma unroll
        for (int r = 0; r < 4; ++r) {
            float s = 0.f;
#pragma unroll
            for (int cf = 0; cf < 8; ++cf) {
                float p = __expf(acc[rb][cf][r] - mrow[rb][r]);
                acc[rb][cf][r] = p;
                s += p;
            }
#pragma unroll
            for (int off = 1; off < 16; off <<= 1) s += __shfl_xor(s, off, 64);
            srow[rb][r] = s;
        }
    if (n16 == 0) {
#pragma unroll
        for (int rb = 0; rb < 4; ++rb)
#pragma unroll
            for (int r = 0; r < 4; ++r)
                red[w * 64 + rb * 16 + quad * 4 + r] = srow[rb][r];
    }
    __syncthreads();
    if (tid < 64) {
        float g = 0.f;
#pragma unroll
        for (int ww = 0; ww < 8; ++ww) g += red[ww * 64 + tid];
        redg[tid] = g;
    }
    __syncthreads();
#pragma unroll
    for (int rb = 0; rb < 4; ++rb)
#pragma unroll
        for (int r = 0; r < 4; ++r)
            srow[rb][r] = 1.0f / redg[rb * 16 + quad * 4 + r];

    // Pack pass-1 P (key-half 1: cf 4..7) to fp16 so acc_qk can die early.
    f16x2 hp[4][4][2];
#pragma unroll
    for (int rb = 0; rb < 4; ++rb)
#pragma unroll
        for (int cb = 0; cb < 4; ++cb)
#pragma unroll
            for (int pr = 0; pr < 2; ++pr) {
                f16x2 t;
                t[0] = (half_t)(acc[rb][4 + cb][2 * pr] * srow[rb][2 * pr]);
                t[1] = (half_t)(acc[rb][4 + cb][2 * pr + 1] * srow[rb][2 * pr + 1]);
                hp[rb][cb][pr] = t;
            }
    __syncthreads();  // all redg reads done; plds (aliases red/redg) writable

    // ================= P pass 0: keys 0..511 -> plds =====================
#pragma unroll
    for (int rb = 0; rb < 4; ++rb)
#pragma unroll
        for (int cb = 0; cb < 4; ++cb) {
            const int cl = w * 64 + cb * 16 + n16;   // local key 0..511
            const int chunk = cl >> 5;
            const int l8 = (cl & 31) >> 3;           // logical slot
            const int c7 = cl & 7;
#pragma unroll
            for (int r = 0; r < 4; ++r) {
                const int lr = rb * 16 + quad * 4 + r;
                const int g = (lr >> 1) & 3;
                plds[chunk * 2048 + lr * 32 + (((l8 ^ g)) << 3) + c7] =
                    (half_t)(acc[rb][cb][r] * srow[rb][r]);
            }
        }
    __syncthreads();

    // ================= PV pass 0: out += P[:,0:512] @ enc ================
    f32x4 accv[4][8];
#pragma unroll
    for (int rb = 0; rb < 4; ++rb)
#pragma unroll
        for (int cb = 0; cb < 8; ++cb) accv[rb][cb] = (f32x4){0.f, 0.f, 0.f, 0.f};

    for (int kcl = 0; kcl < 16; ++kcl) {
        const half_t* tc = encTsw + bofs + (size_t)kcl * 32768;
        f16x8 bf[8];
#pragma unroll
        for (int cb = 0; cb < 8; ++cb)
            bf[cb] = *(const f16x8*)(tc + (w * 128 + cb * 16) * 32 + laneoff);
        f16x8 af[4];
#pragma unroll
        for (int rb = 0; rb < 4; ++rb)
            af[rb] = *(const f16x8*)(plds + kcl * 2048 + aoff[rb]);
#pragma unroll
        for (int rb = 0; rb < 4; ++rb)
#pragma unroll
            for (int cb = 0; cb < 8; ++cb)
                accv[rb][cb] = __builtin_amdgcn_mfma_f32_16x16x32_f16(
                    af[rb], bf[cb], accv[rb][cb], 0, 0, 0);
    }
    __syncthreads();  // pass-0 plds reads done before rewrite

    // ================= P pass 1: keys 512..1023 -> plds ==================
#pragma unroll
    for (int rb = 0; rb < 4; ++rb)
#pragma unroll
        for (int cb = 0; cb < 4; ++cb) {
            const int cl = w * 64 + cb * 16 + n16;   // local key 0..511
            const int chunk = cl >> 5;
            const int l8 = (cl & 31) >> 3;
            const int c7 = cl & 7;
#pragma unroll
            for (int r = 0; r < 4; ++r) {
                const int lr = rb * 16 + quad * 4 + r;
                const int g = (lr >> 1) & 3;
                plds[chunk * 2048 + lr * 32 + (((l8 ^ g)) << 3) + c7] =
                    hp[rb][cb][r >> 1][r & 1];
            }
        }
    __syncthreads();

    // ================ PV pass 1: out += P[:,512:1024] @ enc ==============
    for (int kcl = 0; kcl < 16; ++kcl) {
        const half_t* tc = encTsw + bofs + (size_t)(16 + kcl) * 32768;
        f16x8 bf[8];
#pragma unroll
        for (int cb = 0; cb < 8; ++cb)
            bf[cb] = *(const f16x8*)(tc + (w * 128 + cb * 16) * 32 + laneoff);
        f16x8 af[4];
#pragma unroll
        for (int rb = 0; rb < 4; ++rb)
            af[rb] = *(const f16x8*)(plds + kcl * 2048 + aoff[rb]);
#pragma unroll
        for (int rb = 0; rb < 4; ++rb)
#pragma unroll
            for (int cb = 0; cb < 8; ++cb)
                accv[rb][cb] = __builtin_amdgcn_mfma_f32_16x16x32_f16(
                    af[rb], bf[cb], accv[rb][cb], 0, 0, 0);
    }

    // ======================= store out (fp32) ============================
#pragma unroll
    for (int rb = 0; rb < 4; ++rb)
#pragma unroll
        for (int cb = 0; cb < 8; ++cb)
#pragma unroll
            for (int r = 0; r < 4; ++r) {
                const int row = qbase + rb * 16 + quad * 4 + r;
                const int col = w * 128 + cb * 16 + n16;
                out[bofs + (size_t)row * 1024 + col] = accv[rb][cb][r];
            }
}

extern "C" void kernel_launch(void* const* d_in, const int* in_sizes, int n_in,
                              void* d_out, int out_size, void* d_ws, size_t ws_size,
                              hipStream_t stream) {
    (void)in_sizes; (void)n_in; (void)out_size; (void)ws_size;
    const float* dec = (const float*)d_in[0];   // decoder_hidden  [16,1024,1024] f32
    const float* enc = (const float*)d_in[1];   // encoder_outputs [16,1024,1024] f32
    float* out = (float*)d_out;

    // workspace: encsw | encTsw, 32MiB each (64MiB total)
    half_t* encsw  = (half_t*)d_ws;
    half_t* encTsw = encsw + ((size_t)16 << 20);

    cvt_kernel<<<dim3(16, 16, 16), 256, 0, stream>>>(enc, encsw, encTsw);
    fused_kernel<<<dim3(256), 512, 0, stream>>>(dec, encsw, encTsw, out);
}